// Round 5
// baseline (781.090 us; speedup 1.0000x reference)
//
#include <hip/hip_runtime.h>
#include <hip/hip_bf16.h>

typedef unsigned short u16;
typedef __attribute__((ext_vector_type(8))) short short8;
typedef __attribute__((ext_vector_type(4))) float floatx4;

#define R_PDS 0.18033688f   // r_softplus_0 / sqrt(64)

__device__ __forceinline__ float bf2f(u16 u) {
    union { float f; unsigned int i; } c; c.i = ((unsigned int)u) << 16; return c.f;
}
__device__ __forceinline__ u16 f2b(float f) {
    union { float f; unsigned int i; } c; c.f = f;
    unsigned int r = c.i + 0x7fffu + ((c.i >> 16) & 1u);
    return (u16)(r >> 16);
}
// packed fp32x2 -> bf16x2 (RNE), returns lo=a, hi=b
__device__ __forceinline__ unsigned int pk2(float a, float b) {
    __hip_bfloat162 h = __float22bfloat162_rn(float2{a, b});
    unsigned int u; __builtin_memcpy(&u, &h, 4); return u;
}

// async global->LDS, 16B per lane. LDS dest is wave-uniform base + lane*16.
__device__ __forceinline__ void async16(const u16* g, u16* l) {
    __builtin_amdgcn_global_load_lds(
        (const __attribute__((address_space(1))) unsigned int*)g,
        (__attribute__((address_space(3))) unsigned int*)l, 16, 0, 0);
}

// ---------------- fp32 -> bf16 convert (weights), 4 elems/thread ----------------
__global__ __launch_bounds__(256) void f2b_k(const float* __restrict__ in, u16* __restrict__ out) {
    int i = blockIdx.x * 256 + threadIdx.x;
    float4 v = ((const float4*)in)[i];
    uint2 w;
    w.x = pk2(v.x, v.y);
    w.y = pk2(v.z, v.w);
    ((uint2*)out)[i] = w;
}

// ---------------- flag: is mask nonzero? ----------------
__global__ void zero_flag_k(int* f) { *f = 0; }

__global__ __launch_bounds__(256) void mask_any_k(const float* __restrict__ mask, int* flag) {
    int i = blockIdx.x * 256 + threadIdx.x;
    uint4 u = ((const uint4*)mask)[i];
    unsigned int v = (u.x | u.y | u.z | u.w) & 0x7fffffffu;
    if (v) atomicOr(flag, 1);
}

// ---------------- RMSNorm (row = 1024 fp32) -> bf16 ----------------
__global__ __launch_bounds__(256) void rmsnorm_k(const float* __restrict__ in,
                                                 const float* __restrict__ gscale,
                                                 u16* __restrict__ out) {
    int row = blockIdx.x;
    int t = threadIdx.x, lane = t & 63, wave = t >> 6;
    const float* x = in + (size_t)row * 1024;
    float4 v = *(const float4*)(x + t * 4);
    float ss = v.x*v.x + v.y*v.y + v.z*v.z + v.w*v.w;
    for (int o = 1; o < 64; o <<= 1) ss += __shfl_xor(ss, o, 64);
    __shared__ float red[4];
    if (lane == 0) red[wave] = ss;
    __syncthreads();
    float tot = red[0] + red[1] + red[2] + red[3];
    float inv = rsqrtf(tot * (1.0f / 1024.0f) + 1e-6f);
    float4 s = *(const float4*)(gscale + t * 4);
    uint2 w;
    w.x = pk2(v.x * inv * s.x, v.y * inv * s.y);
    w.y = pk2(v.z * inv * s.z, v.w * inv * s.w);
    *(uint2*)(out + (size_t)row * 1024 + t * 4) = w;
}

// ---------------- LayerNorm (row = 1024 bf16 in, eff scale = 1+s) -> bf16 ----------------
__global__ __launch_bounds__(256) void layernorm_k(const u16* __restrict__ in,
                                                   const float* __restrict__ gs,
                                                   const float* __restrict__ gb,
                                                   u16* __restrict__ out) {
    int row = blockIdx.x;
    int t = threadIdx.x, lane = t & 63, wave = t >> 6;
    const u16* x = in + (size_t)row * 1024;
    uint2 u = *(const uint2*)(x + t * 4);
    float v0 = bf2f((u16)(u.x & 0xffff)), v1 = bf2f((u16)(u.x >> 16));
    float v2 = bf2f((u16)(u.y & 0xffff)), v3 = bf2f((u16)(u.y >> 16));
    float s1 = v0 + v1 + v2 + v3;
    float s2 = v0*v0 + v1*v1 + v2*v2 + v3*v3;
    for (int o = 1; o < 64; o <<= 1) { s1 += __shfl_xor(s1, o, 64); s2 += __shfl_xor(s2, o, 64); }
    __shared__ float r1[4], r2[4];
    if (lane == 0) { r1[wave] = s1; r2[wave] = s2; }
    __syncthreads();
    float mean = (r1[0] + r1[1] + r1[2] + r1[3]) * (1.0f / 1024.0f);
    float var  = (r2[0] + r2[1] + r2[2] + r2[3]) * (1.0f / 1024.0f) - mean * mean;
    var = fmaxf(var, 0.0f);
    float inv = rsqrtf(var + 1e-6f);
    float4 sc = *(const float4*)(gs + t * 4);
    float4 bb = *(const float4*)(gb + t * 4);
    uint2 w;
    w.x = pk2((v0 - mean) * inv * (1.0f + sc.x) + bb.x,
              (v1 - mean) * inv * (1.0f + sc.y) + bb.y);
    w.y = pk2((v2 - mean) * inv * (1.0f + sc.z) + bb.z,
              (v3 - mean) * inv * (1.0f + sc.w) + bb.w);
    *(uint2*)(out + (size_t)row * 1024 + t * 4) = w;
}

// ---------------- GEMM: C[M,N] = A_bf16[M,K] * B_bf16[N,K]^T + bias (+epilogue) --------
// EPI: 0 bias, 1 bias+relu, 2 bias+residual. OUTF32: C fp32 else bf16. RESF32: res dtype.
template <int EPI, bool OUTF32, bool RESF32>
__global__ __launch_bounds__(256) void gemm_bt_k(const u16* __restrict__ A,
                                                 const u16* __restrict__ B,
                                                 const float* __restrict__ bias,
                                                 const void* __restrict__ res,
                                                 void* __restrict__ Cv,
                                                 int M, int N, int K) {
    __shared__ __align__(16) u16 As[4096];   // 128 rows x 32 k (DMA layout, unpadded)
    __shared__ __align__(16) u16 Bs[4096];
    const int t = threadIdx.x, wave = t >> 6, lane = t & 63;
    const int quad = lane >> 4, ln = lane & 15;
    const int m0 = blockIdx.y * 128, n0 = blockIdx.x * 128;
    const int wm = (wave >> 1) * 64, wn = (wave & 1) * 64;

    floatx4 acc[4][4];
    for (int mt = 0; mt < 4; mt++) for (int nt = 0; nt < 4; nt++) acc[mt][nt] = (floatx4)0.0f;

    const int c0 = t, c1 = t + 256;
    const u16* Ap0 = A + (size_t)(m0 + (c0 >> 2)) * K + (c0 & 3) * 8;
    const u16* Ap1 = A + (size_t)(m0 + (c1 >> 2)) * K + (c1 & 3) * 8;
    const u16* Bp0 = B + (size_t)(n0 + (c0 >> 2)) * K + (c0 & 3) * 8;
    const u16* Bp1 = B + (size_t)(n0 + (c1 >> 2)) * K + (c1 & 3) * 8;
    u16* AsW0 = As + wave * 512;
    u16* AsW1 = As + 2048 + wave * 512;
    u16* BsW0 = Bs + wave * 512;
    u16* BsW1 = Bs + 2048 + wave * 512;

    for (int kt = 0; kt < K; kt += 32) {
        __syncthreads();
        async16(Ap0 + kt, AsW0);
        async16(Ap1 + kt, AsW1);
        async16(Bp0 + kt, BsW0);
        async16(Bp1 + kt, BsW1);
        __syncthreads();
        short8 af[4], bfr[4];
        for (int mt = 0; mt < 4; mt++)
            af[mt] = *(const short8*)&As[(wm + mt * 16 + ln) * 32 + quad * 8];
        for (int nt = 0; nt < 4; nt++)
            bfr[nt] = *(const short8*)&Bs[(wn + nt * 16 + ln) * 32 + quad * 8];
        for (int mt = 0; mt < 4; mt++)
            for (int nt = 0; nt < 4; nt++)
                acc[mt][nt] = __builtin_amdgcn_mfma_f32_16x16x32_bf16(af[mt], bfr[nt], acc[mt][nt], 0, 0, 0);
    }

    for (int nt = 0; nt < 4; nt++) {
        int col = n0 + wn + nt * 16 + ln;
        float bv = bias[col];
        for (int mt = 0; mt < 4; mt++) {
            for (int r = 0; r < 4; r++) {
                int row = m0 + wm + mt * 16 + quad * 4 + r;
                float v = acc[mt][nt][r] + bv;
                if (EPI == 1) v = fmaxf(v, 0.0f);
                if (EPI == 2) {
                    if (RESF32) v += ((const float*)res)[(size_t)row * N + col];
                    else        v += bf2f(((const u16*)res)[(size_t)row * N + col]);
                }
                if (OUTF32) ((float*)Cv)[(size_t)row * N + col] = v;
                else        ((u16*)Cv)[(size_t)row * N + col] = f2b(v);
            }
        }
    }
}

// ---------------- fused QKV GEMM: C[8192,3072], q cols scaled by softplus(pds) -------
__global__ __launch_bounds__(256) void gemm_qkv_k(const u16* __restrict__ A,
                                                  const u16* __restrict__ B,
                                                  const float* __restrict__ bq,
                                                  const float* __restrict__ bk,
                                                  const float* __restrict__ bv,
                                                  const float* __restrict__ pds,
                                                  u16* __restrict__ C) {
    const int K = 1024, N = 3072;
    __shared__ __align__(16) u16 As[4096];
    __shared__ __align__(16) u16 Bs[4096];
    const int t = threadIdx.x, wave = t >> 6, lane = t & 63;
    const int quad = lane >> 4, ln = lane & 15;
    const int m0 = blockIdx.y * 128, n0 = blockIdx.x * 128;
    const int wm = (wave >> 1) * 64, wn = (wave & 1) * 64;

    floatx4 acc[4][4];
    for (int mt = 0; mt < 4; mt++) for (int nt = 0; nt < 4; nt++) acc[mt][nt] = (floatx4)0.0f;

    const int c0 = t, c1 = t + 256;
    const u16* Ap0 = A + (size_t)(m0 + (c0 >> 2)) * K + (c0 & 3) * 8;
    const u16* Ap1 = A + (size_t)(m0 + (c1 >> 2)) * K + (c1 & 3) * 8;
    const u16* Bp0 = B + (size_t)(n0 + (c0 >> 2)) * K + (c0 & 3) * 8;
    const u16* Bp1 = B + (size_t)(n0 + (c1 >> 2)) * K + (c1 & 3) * 8;
    u16* AsW0 = As + wave * 512;
    u16* AsW1 = As + 2048 + wave * 512;
    u16* BsW0 = Bs + wave * 512;
    u16* BsW1 = Bs + 2048 + wave * 512;

    for (int kt = 0; kt < K; kt += 32) {
        __syncthreads();
        async16(Ap0 + kt, AsW0);
        async16(Ap1 + kt, AsW1);
        async16(Bp0 + kt, BsW0);
        async16(Bp1 + kt, BsW1);
        __syncthreads();
        short8 af[4], bfr[4];
        for (int mt = 0; mt < 4; mt++)
            af[mt] = *(const short8*)&As[(wm + mt * 16 + ln) * 32 + quad * 8];
        for (int nt = 0; nt < 4; nt++)
            bfr[nt] = *(const short8*)&Bs[(wn + nt * 16 + ln) * 32 + quad * 8];
        for (int mt = 0; mt < 4; mt++)
            for (int nt = 0; nt < 4; nt++)
                acc[mt][nt] = __builtin_amdgcn_mfma_f32_16x16x32_bf16(af[mt], bfr[nt], acc[mt][nt], 0, 0, 0);
    }

    for (int nt = 0; nt < 4; nt++) {
        int col = n0 + wn + nt * 16 + ln;
        float bv_, sc = 1.0f;
        if (col < 1024) {
            bv_ = bq[col];
            float xp = pds[col & 63];
            float sp = (xp > 20.0f) ? xp : log1pf(__expf(xp));
            sc = R_PDS * sp;
        } else if (col < 2048) bv_ = bk[col - 1024];
        else                   bv_ = bv[col - 2048];
        for (int mt = 0; mt < 4; mt++)
            for (int r = 0; r < 4; r++) {
                int row = m0 + wm + mt * 16 + quad * 4 + r;
                C[(size_t)row * N + col] = f2b((acc[mt][nt][r] + bv_) * sc);
            }
    }
}

// ---------------- V transpose: qkv v-part [t][2048+h*64+d] -> vT[bh][d][s] ----------------
__global__ __launch_bounds__(256) void transpose_v_k(const u16* __restrict__ qkv, u16* __restrict__ vT) {
    __shared__ u16 tile[64][65];
    int st = blockIdx.x, bh = blockIdx.y;
    int b = bh >> 4, h = bh & 15;
    const u16* vb = qkv + (size_t)(b * 2048 + st * 64) * 3072 + 2048 + h * 64;
    int t = threadIdx.x;
    for (int i = t; i < 4096; i += 256) {
        int s = i >> 6, d = i & 63;
        tile[s][d] = vb[(size_t)s * 3072 + d];
    }
    __syncthreads();
    u16* ob = vT + (size_t)bh * 131072 + st * 64;
    for (int i = t; i < 4096; i += 256) {
        int d = i >> 6, s = i & 63;
        ob[(size_t)d * 2048 + s] = tile[s][d];
    }
}

// ---------------- flash attention: 1 block = (bh, 64 q rows), BKV=64, 4 blocks/CU ------
__global__ __launch_bounds__(256, 4) void attn_k(const u16* __restrict__ qkv,
                                                 const u16* __restrict__ vT,
                                                 const float* __restrict__ mask,
                                                 const int* __restrict__ flag,
                                                 u16* __restrict__ o) {
    __shared__ __align__(16) u16 Qs[64][72];
    __shared__ __align__(16) u16 Ks[64][72];
    __shared__ __align__(16) u16 Vs[64][72];    // rows = d, cols = kv
    __shared__ __align__(16) u16 Ps[64][72];

    const int t = threadIdx.x, wave = t >> 6, lane = t & 63;
    const int quad = lane >> 4, ln = lane & 15;
    const int qt = blockIdx.x, bh = blockIdx.y;
    const int b = bh >> 4, h = bh & 15;
    const int q0 = qt * 64;

    // stage Q tile (already per-dim scaled in QKV epilogue)
    const u16* qb = qkv + (size_t)(b * 2048 + q0) * 3072 + h * 64;
    for (int c = t; c < 512; c += 256) {
        int row = c >> 3, seg = c & 7;
        *(uint4*)&Qs[row][seg * 8] = *(const uint4*)(qb + (size_t)row * 3072 + seg * 8);
    }
    __syncthreads();

    // hoist Q fragments: wave handles q rows [wave*16, wave*16+16)
    short8 qf[2];
    for (int ks = 0; ks < 2; ks++)
        qf[ks] = *(const short8*)&Qs[wave * 16 + ln][ks * 32 + quad * 8];

    short8 ones_f;
    for (int i = 0; i < 8; i++) ones_f[i] = (short)0x3F80;   // bf16 1.0

    floatx4 acc_o[4], acc_l = (floatx4)0.0f;
    for (int dt = 0; dt < 4; dt++) acc_o[dt] = (floatx4)0.0f;

    const int mflag = *flag;
    const u16* kb = qkv + (size_t)(b * 2048) * 3072 + 1024 + h * 64;
    const u16* vg = vT + (size_t)bh * 131072;

    // prefetch: regs hold next kv tile (K: c<512, V: c>=512)
    uint4 pre[4];
    #pragma unroll
    for (int i = 0; i < 4; i++) {
        int c = t + 256 * i;
        if (c < 512) pre[i] = *(const uint4*)(kb + (size_t)(c >> 3) * 3072 + (c & 7) * 8);
        else { int c2 = c - 512; pre[i] = *(const uint4*)(vg + (size_t)(c2 >> 3) * 2048 + 0 + (c2 & 7) * 8); }
    }

    for (int kv0 = 0; kv0 < 2048; kv0 += 64) {
        __syncthreads();                       // all waves done with prev Ks/Vs
        #pragma unroll
        for (int i = 0; i < 4; i++) {
            int c = t + 256 * i;
            if (c < 512) *(uint4*)&Ks[c >> 3][(c & 7) * 8] = pre[i];
            else { int c2 = c - 512; *(uint4*)&Vs[c2 >> 3][(c2 & 7) * 8] = pre[i]; }
        }
        __syncthreads();
        if (kv0 + 64 < 2048) {
            int nxt = kv0 + 64;
            #pragma unroll
            for (int i = 0; i < 4; i++) {
                int c = t + 256 * i;
                if (c < 512) pre[i] = *(const uint4*)(kb + (size_t)(nxt + (c >> 3)) * 3072 + (c & 7) * 8);
                else { int c2 = c - 512; pre[i] = *(const uint4*)(vg + (size_t)(c2 >> 3) * 2048 + nxt + (c2 & 7) * 8); }
            }
        }

        // S = Q K^T  (wave: 16 q rows x 64 kv cols)
        floatx4 acc_s[4];
        for (int nt = 0; nt < 4; nt++) acc_s[nt] = (floatx4)0.0f;
        for (int ks = 0; ks < 2; ks++)
            for (int nt = 0; nt < 4; nt++) {
                short8 bfr = *(const short8*)&Ks[nt * 16 + ln][ks * 32 + quad * 8];
                acc_s[nt] = __builtin_amdgcn_mfma_f32_16x16x32_bf16(qf[ks], bfr, acc_s[nt], 0, 0, 0);
            }
        if (mflag) {
            for (int nt = 0; nt < 4; nt++)
                for (int r = 0; r < 4; r++) {
                    int qr = q0 + wave * 16 + quad * 4 + r;
                    int kc = kv0 + nt * 16 + ln;
                    acc_s[nt][r] += mask[(size_t)qr * 2048 + kc];
                }
        }

        // P = exp(min(S,60)) -> Ps (bf16), packed cvt; rows are wave-local
        int prow = wave * 16 + quad * 4;
        for (int nt = 0; nt < 4; nt++) {
            unsigned int u01 = pk2(__expf(fminf(acc_s[nt][0], 60.0f)),
                                   __expf(fminf(acc_s[nt][1], 60.0f)));
            unsigned int u23 = pk2(__expf(fminf(acc_s[nt][2], 60.0f)),
                                   __expf(fminf(acc_s[nt][3], 60.0f)));
            Ps[prow + 0][nt * 16 + ln] = (u16)(u01 & 0xffff);
            Ps[prow + 1][nt * 16 + ln] = (u16)(u01 >> 16);
            Ps[prow + 2][nt * 16 + ln] = (u16)(u23 & 0xffff);
            Ps[prow + 3][nt * 16 + ln] = (u16)(u23 >> 16);
        }
        // no barrier: Ps rows [wave*16, wave*16+16) written and read by the same wave

        // O += P V ; l += P·1
        for (int ks = 0; ks < 2; ks++) {
            short8 a = *(const short8*)&Ps[wave * 16 + ln][ks * 32 + quad * 8];
            acc_l = __builtin_amdgcn_mfma_f32_16x16x32_bf16(a, ones_f, acc_l, 0, 0, 0);
            for (int dt = 0; dt < 4; dt++) {
                short8 bfr = *(const short8*)&Vs[dt * 16 + ln][ks * 32 + quad * 8];
                acc_o[dt] = __builtin_amdgcn_mfma_f32_16x16x32_bf16(a, bfr, acc_o[dt], 0, 0, 0);
            }
        }
    }

    // write O -> o[b, s, h, d] bf16 (row stride 1024)
    u16* ob = o + (size_t)(b * 2048 + q0) * 1024 + h * 64;
    for (int r = 0; r < 4; r++) {
        float inv = 1.0f / acc_l[r];
        int row = wave * 16 + quad * 4 + r;
        for (int dt = 0; dt < 4; dt++)
            ob[(size_t)row * 1024 + dt * 16 + ln] = f2b(acc_o[dt][r] * inv);
    }
}

extern "C" void kernel_launch(void* const* d_in, const int* in_sizes, int n_in,
                              void* d_out, int out_size, void* d_ws, size_t ws_size,
                              hipStream_t stream) {
    const float* inp    = (const float*)d_in[0];
    const float* mask   = (const float*)d_in[1];
    const float* rms_s  = (const float*)d_in[2];
    const float* Wq     = (const float*)d_in[3];
    const float* bq     = (const float*)d_in[4];
    const float* Wk     = (const float*)d_in[5];
    const float* bk     = (const float*)d_in[6];
    const float* Wv     = (const float*)d_in[7];
    const float* bv     = (const float*)d_in[8];
    const float* pds    = (const float*)d_in[9];
    const float* Wpost  = (const float*)d_in[10];
    const float* bpost  = (const float*)d_in[11];
    const float* ln_s   = (const float*)d_in[12];
    const float* ln_b   = (const float*)d_in[13];
    const float* W1     = (const float*)d_in[14];
    const float* b1     = (const float*)d_in[15];
    const float* W2     = (const float*)d_in[16];
    const float* b2     = (const float*)d_in[17];
    float* out = (float*)d_out;

    char* w = (char*)d_ws;
    const size_t MB = 1u << 20;
    // Phase-lifetime layout (112 MB exact):
    // [0,8)   W1b            (pre..FFN1)
    // [8,16)  W2b            (pre..FFN2)
    // [16,64) qkv            (QKV..attn)     -> f1 [16,80) (FFN1..FFN2)
    // [64,80) x (rms..QKV)   -> o (attn..post)
    // [80,86) Wqkvb (pre..QKV), [86,88) Wpb (pre..post) -> yln [80,96) (ln..FFN1)
    // [96,112) vT (transpose..attn) -> hb (post..FFN2)
    // flag @112MB
    u16* W1b   = (u16*)(w + 0 * MB);
    u16* W2b   = (u16*)(w + 8 * MB);
    u16* qkv   = (u16*)(w + 16 * MB);
    u16* x     = (u16*)(w + 64 * MB);
    u16* o     = (u16*)(w + 64 * MB);
    u16* Wqkvb = (u16*)(w + 80 * MB);
    u16* Wpb   = (u16*)(w + 86 * MB);
    u16* yln   = (u16*)(w + 80 * MB);
    u16* vT    = (u16*)(w + 96 * MB);
    u16* hb    = (u16*)(w + 96 * MB);
    u16* f1    = (u16*)(w + 16 * MB);
    int* flag  = (int*)(w + 112 * MB);

    // weight pre-convert (fp32 -> bf16); Wq/Wk/Wv concatenated row-wise
    f2b_k<<<1024, 256, 0, stream>>>(Wq, Wqkvb);
    f2b_k<<<1024, 256, 0, stream>>>(Wk, Wqkvb + 1024 * 1024);
    f2b_k<<<1024, 256, 0, stream>>>(Wv, Wqkvb + 2 * 1024 * 1024);
    f2b_k<<<1024, 256, 0, stream>>>(Wpost, Wpb);
    f2b_k<<<4096, 256, 0, stream>>>(W1, W1b);
    f2b_k<<<4096, 256, 0, stream>>>(W2, W2b);

    zero_flag_k<<<1, 1, 0, stream>>>(flag);
    mask_any_k<<<4096, 256, 0, stream>>>(mask, flag);

    rmsnorm_k<<<8192, 256, 0, stream>>>(inp, rms_s, x);

    gemm_qkv_k<<<dim3(24, 64), 256, 0, stream>>>(x, Wqkvb, bq, bk, bv, pds, qkv);

    transpose_v_k<<<dim3(32, 64), 256, 0, stream>>>(qkv, vT);

    attn_k<<<dim3(32, 64), 256, 0, stream>>>(qkv, vT, mask, flag, o);

    gemm_bt_k<2, false, true><<<dim3(8, 64), 256, 0, stream>>>(o, Wpb, bpost, inp, hb, 8192, 1024, 1024);

    layernorm_k<<<8192, 256, 0, stream>>>(hb, ln_s, ln_b, yln);

    gemm_bt_k<1, false, true><<<dim3(32, 64), 256, 0, stream>>>(yln, W1b, b1, nullptr, f1, 8192, 4096, 1024);
    gemm_bt_k<2, true, false><<<dim3(8, 64), 256, 0, stream>>>(f1, W2b, b2, hb, out, 8192, 1024, 4096);
}

// Round 6
// 632.164 us; speedup vs baseline: 1.2356x; 1.2356x over previous
//
#include <hip/hip_runtime.h>
#include <hip/hip_bf16.h>

typedef unsigned short u16;
typedef __attribute__((ext_vector_type(8))) short short8;
typedef __attribute__((ext_vector_type(4))) float floatx4;

#define R_PDS 0.18033688f   // r_softplus_0 / sqrt(64)

__device__ __forceinline__ float bf2f(u16 u) {
    union { float f; unsigned int i; } c; c.i = ((unsigned int)u) << 16; return c.f;
}
__device__ __forceinline__ u16 f2b(float f) {
    union { float f; unsigned int i; } c; c.f = f;
    unsigned int r = c.i + 0x7fffu + ((c.i >> 16) & 1u);
    return (u16)(r >> 16);
}
// packed fp32x2 -> bf16x2 (RNE), returns lo=a, hi=b
__device__ __forceinline__ unsigned int pk2(float a, float b) {
    __hip_bfloat162 h = __float22bfloat162_rn(float2{a, b});
    unsigned int u; __builtin_memcpy(&u, &h, 4); return u;
}

// async global->LDS, 16B per lane. LDS dest is wave-uniform base + lane*16.
__device__ __forceinline__ void async16(const u16* g, u16* l) {
    __builtin_amdgcn_global_load_lds(
        (const __attribute__((address_space(1))) unsigned int*)g,
        (__attribute__((address_space(3))) unsigned int*)l, 16, 0, 0);
}

// ---------------- fp32 -> bf16 convert (weights), 4 elems/thread ----------------
__global__ __launch_bounds__(256) void f2b_k(const float* __restrict__ in, u16* __restrict__ out) {
    int i = blockIdx.x * 256 + threadIdx.x;
    float4 v = ((const float4*)in)[i];
    uint2 w;
    w.x = pk2(v.x, v.y);
    w.y = pk2(v.z, v.w);
    ((uint2*)out)[i] = w;
}

// ---------------- flag: is mask nonzero? ----------------
__global__ void zero_flag_k(int* f) { *f = 0; }

__global__ __launch_bounds__(256) void mask_any_k(const float* __restrict__ mask, int* flag) {
    int i = blockIdx.x * 256 + threadIdx.x;
    uint4 u = ((const uint4*)mask)[i];
    unsigned int v = (u.x | u.y | u.z | u.w) & 0x7fffffffu;
    if (v) atomicOr(flag, 1);
}

// ---------------- RMSNorm (row = 1024 fp32) -> bf16 ----------------
__global__ __launch_bounds__(256) void rmsnorm_k(const float* __restrict__ in,
                                                 const float* __restrict__ gscale,
                                                 u16* __restrict__ out) {
    int row = blockIdx.x;
    int t = threadIdx.x, lane = t & 63, wave = t >> 6;
    const float* x = in + (size_t)row * 1024;
    float4 v = *(const float4*)(x + t * 4);
    float ss = v.x*v.x + v.y*v.y + v.z*v.z + v.w*v.w;
    for (int o = 1; o < 64; o <<= 1) ss += __shfl_xor(ss, o, 64);
    __shared__ float red[4];
    if (lane == 0) red[wave] = ss;
    __syncthreads();
    float tot = red[0] + red[1] + red[2] + red[3];
    float inv = rsqrtf(tot * (1.0f / 1024.0f) + 1e-6f);
    float4 s = *(const float4*)(gscale + t * 4);
    uint2 w;
    w.x = pk2(v.x * inv * s.x, v.y * inv * s.y);
    w.y = pk2(v.z * inv * s.z, v.w * inv * s.w);
    *(uint2*)(out + (size_t)row * 1024 + t * 4) = w;
}

// ---------------- LayerNorm (row = 1024 bf16 in, eff scale = 1+s) -> bf16 ----------------
__global__ __launch_bounds__(256) void layernorm_k(const u16* __restrict__ in,
                                                   const float* __restrict__ gs,
                                                   const float* __restrict__ gb,
                                                   u16* __restrict__ out) {
    int row = blockIdx.x;
    int t = threadIdx.x, lane = t & 63, wave = t >> 6;
    const u16* x = in + (size_t)row * 1024;
    uint2 u = *(const uint2*)(x + t * 4);
    float v0 = bf2f((u16)(u.x & 0xffff)), v1 = bf2f((u16)(u.x >> 16));
    float v2 = bf2f((u16)(u.y & 0xffff)), v3 = bf2f((u16)(u.y >> 16));
    float s1 = v0 + v1 + v2 + v3;
    float s2 = v0*v0 + v1*v1 + v2*v2 + v3*v3;
    for (int o = 1; o < 64; o <<= 1) { s1 += __shfl_xor(s1, o, 64); s2 += __shfl_xor(s2, o, 64); }
    __shared__ float r1[4], r2[4];
    if (lane == 0) { r1[wave] = s1; r2[wave] = s2; }
    __syncthreads();
    float mean = (r1[0] + r1[1] + r1[2] + r1[3]) * (1.0f / 1024.0f);
    float var  = (r2[0] + r2[1] + r2[2] + r2[3]) * (1.0f / 1024.0f) - mean * mean;
    var = fmaxf(var, 0.0f);
    float inv = rsqrtf(var + 1e-6f);
    float4 sc = *(const float4*)(gs + t * 4);
    float4 bb = *(const float4*)(gb + t * 4);
    uint2 w;
    w.x = pk2((v0 - mean) * inv * (1.0f + sc.x) + bb.x,
              (v1 - mean) * inv * (1.0f + sc.y) + bb.y);
    w.y = pk2((v2 - mean) * inv * (1.0f + sc.z) + bb.z,
              (v3 - mean) * inv * (1.0f + sc.w) + bb.w);
    *(uint2*)(out + (size_t)row * 1024 + t * 4) = w;
}

// ---------------- GEMM: C[M,N] = A_bf16[M,K] * B_bf16[N,K]^T + bias (+epilogue) --------
// EPI: 0 bias, 1 bias+relu, 2 bias+residual. OUTF32: C fp32 else bf16. RESF32: res dtype.
template <int EPI, bool OUTF32, bool RESF32>
__global__ __launch_bounds__(256) void gemm_bt_k(const u16* __restrict__ A,
                                                 const u16* __restrict__ B,
                                                 const float* __restrict__ bias,
                                                 const void* __restrict__ res,
                                                 void* __restrict__ Cv,
                                                 int M, int N, int K) {
    __shared__ __align__(16) u16 As[4096];   // 128 rows x 32 k (DMA layout, unpadded)
    __shared__ __align__(16) u16 Bs[4096];
    const int t = threadIdx.x, wave = t >> 6, lane = t & 63;
    const int quad = lane >> 4, ln = lane & 15;
    const int m0 = blockIdx.y * 128, n0 = blockIdx.x * 128;
    const int wm = (wave >> 1) * 64, wn = (wave & 1) * 64;

    floatx4 acc[4][4];
    for (int mt = 0; mt < 4; mt++) for (int nt = 0; nt < 4; nt++) acc[mt][nt] = (floatx4)0.0f;

    const int c0 = t, c1 = t + 256;
    const u16* Ap0 = A + (size_t)(m0 + (c0 >> 2)) * K + (c0 & 3) * 8;
    const u16* Ap1 = A + (size_t)(m0 + (c1 >> 2)) * K + (c1 & 3) * 8;
    const u16* Bp0 = B + (size_t)(n0 + (c0 >> 2)) * K + (c0 & 3) * 8;
    const u16* Bp1 = B + (size_t)(n0 + (c1 >> 2)) * K + (c1 & 3) * 8;
    u16* AsW0 = As + wave * 512;
    u16* AsW1 = As + 2048 + wave * 512;
    u16* BsW0 = Bs + wave * 512;
    u16* BsW1 = Bs + 2048 + wave * 512;

    for (int kt = 0; kt < K; kt += 32) {
        __syncthreads();
        async16(Ap0 + kt, AsW0);
        async16(Ap1 + kt, AsW1);
        async16(Bp0 + kt, BsW0);
        async16(Bp1 + kt, BsW1);
        __syncthreads();
        short8 af[4], bfr[4];
        for (int mt = 0; mt < 4; mt++)
            af[mt] = *(const short8*)&As[(wm + mt * 16 + ln) * 32 + quad * 8];
        for (int nt = 0; nt < 4; nt++)
            bfr[nt] = *(const short8*)&Bs[(wn + nt * 16 + ln) * 32 + quad * 8];
        for (int mt = 0; mt < 4; mt++)
            for (int nt = 0; nt < 4; nt++)
                acc[mt][nt] = __builtin_amdgcn_mfma_f32_16x16x32_bf16(af[mt], bfr[nt], acc[mt][nt], 0, 0, 0);
    }

    for (int nt = 0; nt < 4; nt++) {
        int col = n0 + wn + nt * 16 + ln;
        float bv = bias[col];
        for (int mt = 0; mt < 4; mt++) {
            for (int r = 0; r < 4; r++) {
                int row = m0 + wm + mt * 16 + quad * 4 + r;
                float v = acc[mt][nt][r] + bv;
                if (EPI == 1) v = fmaxf(v, 0.0f);
                if (EPI == 2) {
                    if (RESF32) v += ((const float*)res)[(size_t)row * N + col];
                    else        v += bf2f(((const u16*)res)[(size_t)row * N + col]);
                }
                if (OUTF32) ((float*)Cv)[(size_t)row * N + col] = v;
                else        ((u16*)Cv)[(size_t)row * N + col] = f2b(v);
            }
        }
    }
}

// ---------------- fused QKV GEMM: C[8192,3072], q cols scaled by softplus(pds) -------
__global__ __launch_bounds__(256) void gemm_qkv_k(const u16* __restrict__ A,
                                                  const u16* __restrict__ B,
                                                  const float* __restrict__ bq,
                                                  const float* __restrict__ bk,
                                                  const float* __restrict__ bv,
                                                  const float* __restrict__ pds,
                                                  u16* __restrict__ C) {
    const int K = 1024, N = 3072;
    __shared__ __align__(16) u16 As[4096];
    __shared__ __align__(16) u16 Bs[4096];
    const int t = threadIdx.x, wave = t >> 6, lane = t & 63;
    const int quad = lane >> 4, ln = lane & 15;
    const int m0 = blockIdx.y * 128, n0 = blockIdx.x * 128;
    const int wm = (wave >> 1) * 64, wn = (wave & 1) * 64;

    floatx4 acc[4][4];
    for (int mt = 0; mt < 4; mt++) for (int nt = 0; nt < 4; nt++) acc[mt][nt] = (floatx4)0.0f;

    const int c0 = t, c1 = t + 256;
    const u16* Ap0 = A + (size_t)(m0 + (c0 >> 2)) * K + (c0 & 3) * 8;
    const u16* Ap1 = A + (size_t)(m0 + (c1 >> 2)) * K + (c1 & 3) * 8;
    const u16* Bp0 = B + (size_t)(n0 + (c0 >> 2)) * K + (c0 & 3) * 8;
    const u16* Bp1 = B + (size_t)(n0 + (c1 >> 2)) * K + (c1 & 3) * 8;
    u16* AsW0 = As + wave * 512;
    u16* AsW1 = As + 2048 + wave * 512;
    u16* BsW0 = Bs + wave * 512;
    u16* BsW1 = Bs + 2048 + wave * 512;

    for (int kt = 0; kt < K; kt += 32) {
        __syncthreads();
        async16(Ap0 + kt, AsW0);
        async16(Ap1 + kt, AsW1);
        async16(Bp0 + kt, BsW0);
        async16(Bp1 + kt, BsW1);
        __syncthreads();
        short8 af[4], bfr[4];
        for (int mt = 0; mt < 4; mt++)
            af[mt] = *(const short8*)&As[(wm + mt * 16 + ln) * 32 + quad * 8];
        for (int nt = 0; nt < 4; nt++)
            bfr[nt] = *(const short8*)&Bs[(wn + nt * 16 + ln) * 32 + quad * 8];
        for (int mt = 0; mt < 4; mt++)
            for (int nt = 0; nt < 4; nt++)
                acc[mt][nt] = __builtin_amdgcn_mfma_f32_16x16x32_bf16(af[mt], bfr[nt], acc[mt][nt], 0, 0, 0);
    }

    for (int nt = 0; nt < 4; nt++) {
        int col = n0 + wn + nt * 16 + ln;
        float bv_, sc = 1.0f;
        if (col < 1024) {
            bv_ = bq[col];
            float xp = pds[col & 63];
            float sp = (xp > 20.0f) ? xp : log1pf(__expf(xp));
            sc = R_PDS * sp;
        } else if (col < 2048) bv_ = bk[col - 1024];
        else                   bv_ = bv[col - 2048];
        for (int mt = 0; mt < 4; mt++)
            for (int r = 0; r < 4; r++) {
                int row = m0 + wm + mt * 16 + quad * 4 + r;
                C[(size_t)row * N + col] = f2b((acc[mt][nt][r] + bv_) * sc);
            }
    }
}

// ---------------- V transpose: qkv v-part [t][2048+h*64+d] -> vT[bh][d][s] ----------------
__global__ __launch_bounds__(256) void transpose_v_k(const u16* __restrict__ qkv, u16* __restrict__ vT) {
    __shared__ u16 tile[64][65];
    int st = blockIdx.x, bh = blockIdx.y;
    int b = bh >> 4, h = bh & 15;
    const u16* vb = qkv + (size_t)(b * 2048 + st * 64) * 3072 + 2048 + h * 64;
    int t = threadIdx.x;
    for (int i = t; i < 4096; i += 256) {
        int s = i >> 6, d = i & 63;
        tile[s][d] = vb[(size_t)s * 3072 + d];
    }
    __syncthreads();
    u16* ob = vT + (size_t)bh * 131072 + st * 64;
    for (int i = t; i < 4096; i += 256) {
        int d = i >> 6, s = i & 63;
        ob[(size_t)d * 2048 + s] = tile[s][d];
    }
}

// ---------------- flash attention: 1 block = (bh, 64 q rows), BKV=64 -------------------
// LDS 36.9 KB -> 4 blocks/CU. Plain uint4 staging (NO register prefetch: r5's pre[]
// spilled to scratch under launch_bounds(256,4) -> 851 MB of HBM writes, 1.8x slower).
__global__ __launch_bounds__(256) void attn_k(const u16* __restrict__ qkv,
                                              const u16* __restrict__ vT,
                                              const float* __restrict__ mask,
                                              const int* __restrict__ flag,
                                              u16* __restrict__ o) {
    __shared__ __align__(16) u16 Qs[64][72];
    __shared__ __align__(16) u16 Ks[64][72];
    __shared__ __align__(16) u16 Vs[64][72];    // rows = d, cols = kv
    __shared__ __align__(16) u16 Ps[64][72];

    const int t = threadIdx.x, wave = t >> 6, lane = t & 63;
    const int quad = lane >> 4, ln = lane & 15;
    const int qt = blockIdx.x, bh = blockIdx.y;
    const int b = bh >> 4, h = bh & 15;
    const int q0 = qt * 64;

    // stage Q tile (already per-dim scaled in QKV epilogue)
    const u16* qb = qkv + (size_t)(b * 2048 + q0) * 3072 + h * 64;
    for (int c = t; c < 512; c += 256) {
        int row = c >> 3, seg = c & 7;
        *(uint4*)&Qs[row][seg * 8] = *(const uint4*)(qb + (size_t)row * 3072 + seg * 8);
    }
    __syncthreads();

    // hoist Q fragments: wave handles q rows [wave*16, wave*16+16)
    short8 qf[2];
    for (int ks = 0; ks < 2; ks++)
        qf[ks] = *(const short8*)&Qs[wave * 16 + ln][ks * 32 + quad * 8];

    short8 ones_f;
    for (int i = 0; i < 8; i++) ones_f[i] = (short)0x3F80;   // bf16 1.0

    floatx4 acc_o[4], acc_l = (floatx4)0.0f;
    for (int dt = 0; dt < 4; dt++) acc_o[dt] = (floatx4)0.0f;

    const int mflag = *flag;
    const u16* kb = qkv + (size_t)(b * 2048) * 3072 + 1024 + h * 64;
    const u16* vg = vT + (size_t)bh * 131072;

    for (int kv0 = 0; kv0 < 2048; kv0 += 64) {
        __syncthreads();                       // all waves done with prev Ks/Vs
        for (int c = t; c < 512; c += 256) {   // K tile: 64 rows x 64, stride 3072
            int row = c >> 3, seg = c & 7;
            *(uint4*)&Ks[row][seg * 8] = *(const uint4*)(kb + (size_t)(kv0 + row) * 3072 + seg * 8);
            *(uint4*)&Vs[row][seg * 8] = *(const uint4*)(vg + (size_t)row * 2048 + kv0 + seg * 8);
        }
        __syncthreads();

        // S = Q K^T  (wave: 16 q rows x 64 kv cols)
        floatx4 acc_s[4];
        for (int nt = 0; nt < 4; nt++) acc_s[nt] = (floatx4)0.0f;
        for (int ks = 0; ks < 2; ks++)
            for (int nt = 0; nt < 4; nt++) {
                short8 bfr = *(const short8*)&Ks[nt * 16 + ln][ks * 32 + quad * 8];
                acc_s[nt] = __builtin_amdgcn_mfma_f32_16x16x32_bf16(qf[ks], bfr, acc_s[nt], 0, 0, 0);
            }
        if (mflag) {
            for (int nt = 0; nt < 4; nt++)
                for (int r = 0; r < 4; r++) {
                    int qr = q0 + wave * 16 + quad * 4 + r;
                    int kc = kv0 + nt * 16 + ln;
                    acc_s[nt][r] += mask[(size_t)qr * 2048 + kc];
                }
        }

        // P = exp(min(S,60)) -> Ps (bf16), packed cvt; rows are wave-local
        int prow = wave * 16 + quad * 4;
        for (int nt = 0; nt < 4; nt++) {
            unsigned int u01 = pk2(__expf(fminf(acc_s[nt][0], 60.0f)),
                                   __expf(fminf(acc_s[nt][1], 60.0f)));
            unsigned int u23 = pk2(__expf(fminf(acc_s[nt][2], 60.0f)),
                                   __expf(fminf(acc_s[nt][3], 60.0f)));
            Ps[prow + 0][nt * 16 + ln] = (u16)(u01 & 0xffff);
            Ps[prow + 1][nt * 16 + ln] = (u16)(u01 >> 16);
            Ps[prow + 2][nt * 16 + ln] = (u16)(u23 & 0xffff);
            Ps[prow + 3][nt * 16 + ln] = (u16)(u23 >> 16);
        }
        // no barrier: Ps rows [wave*16, wave*16+16) written and read by the same wave

        // O += P V ; l += P·1
        for (int ks = 0; ks < 2; ks++) {
            short8 a = *(const short8*)&Ps[wave * 16 + ln][ks * 32 + quad * 8];
            acc_l = __builtin_amdgcn_mfma_f32_16x16x32_bf16(a, ones_f, acc_l, 0, 0, 0);
            for (int dt = 0; dt < 4; dt++) {
                short8 bfr = *(const short8*)&Vs[dt * 16 + ln][ks * 32 + quad * 8];
                acc_o[dt] = __builtin_amdgcn_mfma_f32_16x16x32_bf16(a, bfr, acc_o[dt], 0, 0, 0);
            }
        }
    }

    // write O -> o[b, s, h, d] bf16 (row stride 1024)
    u16* ob = o + (size_t)(b * 2048 + q0) * 1024 + h * 64;
    for (int r = 0; r < 4; r++) {
        float inv = 1.0f / acc_l[r];
        int row = wave * 16 + quad * 4 + r;
        for (int dt = 0; dt < 4; dt++)
            ob[(size_t)row * 1024 + dt * 16 + ln] = f2b(acc_o[dt][r] * inv);
    }
}

extern "C" void kernel_launch(void* const* d_in, const int* in_sizes, int n_in,
                              void* d_out, int out_size, void* d_ws, size_t ws_size,
                              hipStream_t stream) {
    const float* inp    = (const float*)d_in[0];
    const float* mask   = (const float*)d_in[1];
    const float* rms_s  = (const float*)d_in[2];
    const float* Wq     = (const float*)d_in[3];
    const float* bq     = (const float*)d_in[4];
    const float* Wk     = (const float*)d_in[5];
    const float* bk     = (const float*)d_in[6];
    const float* Wv     = (const float*)d_in[7];
    const float* bv     = (const float*)d_in[8];
    const float* pds    = (const float*)d_in[9];
    const float* Wpost  = (const float*)d_in[10];
    const float* bpost  = (const float*)d_in[11];
    const float* ln_s   = (const float*)d_in[12];
    const float* ln_b   = (const float*)d_in[13];
    const float* W1     = (const float*)d_in[14];
    const float* b1     = (const float*)d_in[15];
    const float* W2     = (const float*)d_in[16];
    const float* b2     = (const float*)d_in[17];
    float* out = (float*)d_out;

    char* w = (char*)d_ws;
    const size_t MB = 1u << 20;
    // Phase-lifetime layout (112 MB exact):
    // [0,8)   W1b            (pre..FFN1)
    // [8,16)  W2b            (pre..FFN2)
    // [16,64) qkv            (QKV..attn)     -> f1 [16,80) (FFN1..FFN2)
    // [64,80) x (rms..QKV)   -> o (attn..post)
    // [80,86) Wqkvb (pre..QKV), [86,88) Wpb (pre..post) -> yln [80,96) (ln..FFN1)
    // [96,112) vT (transpose..attn) -> hb (post..FFN2)
    // flag @112MB
    u16* W1b   = (u16*)(w + 0 * MB);
    u16* W2b   = (u16*)(w + 8 * MB);
    u16* qkv   = (u16*)(w + 16 * MB);
    u16* x     = (u16*)(w + 64 * MB);
    u16* o     = (u16*)(w + 64 * MB);
    u16* Wqkvb = (u16*)(w + 80 * MB);
    u16* Wpb   = (u16*)(w + 86 * MB);
    u16* yln   = (u16*)(w + 80 * MB);
    u16* vT    = (u16*)(w + 96 * MB);
    u16* hb    = (u16*)(w + 96 * MB);
    u16* f1    = (u16*)(w + 16 * MB);
    int* flag  = (int*)(w + 112 * MB);

    // weight pre-convert (fp32 -> bf16); Wq/Wk/Wv concatenated row-wise
    f2b_k<<<1024, 256, 0, stream>>>(Wq, Wqkvb);
    f2b_k<<<1024, 256, 0, stream>>>(Wk, Wqkvb + 1024 * 1024);
    f2b_k<<<1024, 256, 0, stream>>>(Wv, Wqkvb + 2 * 1024 * 1024);
    f2b_k<<<1024, 256, 0, stream>>>(Wpost, Wpb);
    f2b_k<<<4096, 256, 0, stream>>>(W1, W1b);
    f2b_k<<<4096, 256, 0, stream>>>(W2, W2b);

    zero_flag_k<<<1, 1, 0, stream>>>(flag);
    mask_any_k<<<4096, 256, 0, stream>>>(mask, flag);

    rmsnorm_k<<<8192, 256, 0, stream>>>(inp, rms_s, x);

    gemm_qkv_k<<<dim3(24, 64), 256, 0, stream>>>(x, Wqkvb, bq, bk, bv, pds, qkv);

    transpose_v_k<<<dim3(32, 64), 256, 0, stream>>>(qkv, vT);

    attn_k<<<dim3(32, 64), 256, 0, stream>>>(qkv, vT, mask, flag, o);

    gemm_bt_k<2, false, true><<<dim3(8, 64), 256, 0, stream>>>(o, Wpb, bpost, inp, hb, 8192, 1024, 1024);

    layernorm_k<<<8192, 256, 0, stream>>>(hb, ln_s, ln_b, yln);

    gemm_bt_k<1, false, true><<<dim3(32, 64), 256, 0, stream>>>(yln, W1b, b1, nullptr, f1, 8192, 4096, 1024);
    gemm_bt_k<2, true, false><<<dim3(8, 64), 256, 0, stream>>>(f1, W2b, b2, hb, out, 8192, 1024, 4096);
}

// Round 7
// 614.610 us; speedup vs baseline: 1.2709x; 1.0286x over previous
//
#include <hip/hip_runtime.h>
#include <hip/hip_bf16.h>

typedef unsigned short u16;
typedef __attribute__((ext_vector_type(8))) short short8;
typedef __attribute__((ext_vector_type(4))) float floatx4;

#define R_PDS 0.18033688f     // r_softplus_0 / sqrt(64)
#define LOG2E 1.4426950408889634f

__device__ __forceinline__ float bf2f(u16 u) {
    union { float f; unsigned int i; } c; c.i = ((unsigned int)u) << 16; return c.f;
}
__device__ __forceinline__ u16 f2b(float f) {
    union { float f; unsigned int i; } c; c.f = f;
    unsigned int r = c.i + 0x7fffu + ((c.i >> 16) & 1u);
    return (u16)(r >> 16);
}
// packed fp32x2 -> bf16x2 (RNE), lo=a hi=b
__device__ __forceinline__ unsigned int pk2(float a, float b) {
    __hip_bfloat162 h = __float22bfloat162_rn(float2{a, b});
    unsigned int u; __builtin_memcpy(&u, &h, 4); return u;
}

// async global->LDS, 16B per lane. LDS dest is wave-uniform base + lane*16.
__device__ __forceinline__ void async16(const u16* g, u16* l) {
    __builtin_amdgcn_global_load_lds(
        (const __attribute__((address_space(1))) unsigned int*)g,
        (__attribute__((address_space(3))) unsigned int*)l, 16, 0, 0);
}

// ---------------- all weight fp32->bf16 converts in ONE kernel (+flag zero) ------------
// segments (in 1024-block units of 256 thr x 4 float4): Wq,Wk,Wv(1024 ea) Wp(1024) W1,W2(4096 ea)
__global__ __launch_bounds__(256) void f2b_all_k(const float* __restrict__ Wq, const float* __restrict__ Wk,
                                                 const float* __restrict__ Wv, const float* __restrict__ Wp,
                                                 const float* __restrict__ W1, const float* __restrict__ W2,
                                                 u16* __restrict__ Wqkvb, u16* __restrict__ Wpb,
                                                 u16* __restrict__ W1b,  u16* __restrict__ W2b,
                                                 int* flag) {
    int bid = blockIdx.x;
    if (bid == 0 && threadIdx.x == 0) *flag = 0;
    const float* src; u16* dst; int off;
    if      (bid < 1024) { src = Wq; dst = Wqkvb;                off = bid; }
    else if (bid < 2048) { src = Wk; dst = Wqkvb + 1024 * 1024;  off = bid - 1024; }
    else if (bid < 3072) { src = Wv; dst = Wqkvb + 2048 * 1024;  off = bid - 2048; }
    else if (bid < 4096) { src = Wp; dst = Wpb;                  off = bid - 3072; }
    else if (bid < 8192) { src = W1; dst = W1b;                  off = bid - 4096; }
    else                 { src = W2; dst = W2b;                  off = bid - 8192; }
    int i = off * 256 + threadIdx.x;
    float4 v = ((const float4*)src)[i];
    uint2 w; w.x = pk2(v.x, v.y); w.y = pk2(v.z, v.w);
    ((uint2*)dst)[i] = w;
}

__global__ __launch_bounds__(256) void mask_any_k(const float* __restrict__ mask, int* flag) {
    int i = blockIdx.x * 256 + threadIdx.x;
    uint4 u = ((const uint4*)mask)[i];
    unsigned int v = (u.x | u.y | u.z | u.w) & 0x7fffffffu;
    if (v) atomicOr(flag, 1);
}

// ---------------- RMSNorm (row = 1024 fp32) -> bf16 ----------------
__global__ __launch_bounds__(256) void rmsnorm_k(const float* __restrict__ in,
                                                 const float* __restrict__ gscale,
                                                 u16* __restrict__ out) {
    int row = blockIdx.x;
    int t = threadIdx.x, lane = t & 63, wave = t >> 6;
    const float* x = in + (size_t)row * 1024;
    float4 v = *(const float4*)(x + t * 4);
    float ss = v.x*v.x + v.y*v.y + v.z*v.z + v.w*v.w;
    for (int o = 1; o < 64; o <<= 1) ss += __shfl_xor(ss, o, 64);
    __shared__ float red[4];
    if (lane == 0) red[wave] = ss;
    __syncthreads();
    float tot = red[0] + red[1] + red[2] + red[3];
    float inv = rsqrtf(tot * (1.0f / 1024.0f) + 1e-6f);
    float4 s = *(const float4*)(gscale + t * 4);
    uint2 w;
    w.x = pk2(v.x * inv * s.x, v.y * inv * s.y);
    w.y = pk2(v.z * inv * s.z, v.w * inv * s.w);
    *(uint2*)(out + (size_t)row * 1024 + t * 4) = w;
}

// ---------------- LayerNorm (row = 1024 bf16 in, eff scale = 1+s) -> bf16 ----------------
__global__ __launch_bounds__(256) void layernorm_k(const u16* __restrict__ in,
                                                   const float* __restrict__ gs,
                                                   const float* __restrict__ gb,
                                                   u16* __restrict__ out) {
    int row = blockIdx.x;
    int t = threadIdx.x, lane = t & 63, wave = t >> 6;
    const u16* x = in + (size_t)row * 1024;
    uint2 u = *(const uint2*)(x + t * 4);
    float v0 = bf2f((u16)(u.x & 0xffff)), v1 = bf2f((u16)(u.x >> 16));
    float v2 = bf2f((u16)(u.y & 0xffff)), v3 = bf2f((u16)(u.y >> 16));
    float s1 = v0 + v1 + v2 + v3;
    float s2 = v0*v0 + v1*v1 + v2*v2 + v3*v3;
    for (int o = 1; o < 64; o <<= 1) { s1 += __shfl_xor(s1, o, 64); s2 += __shfl_xor(s2, o, 64); }
    __shared__ float r1[4], r2[4];
    if (lane == 0) { r1[wave] = s1; r2[wave] = s2; }
    __syncthreads();
    float mean = (r1[0] + r1[1] + r1[2] + r1[3]) * (1.0f / 1024.0f);
    float var  = (r2[0] + r2[1] + r2[2] + r2[3]) * (1.0f / 1024.0f) - mean * mean;
    var = fmaxf(var, 0.0f);
    float inv = rsqrtf(var + 1e-6f);
    float4 sc = *(const float4*)(gs + t * 4);
    float4 bb = *(const float4*)(gb + t * 4);
    uint2 w;
    w.x = pk2((v0 - mean) * inv * (1.0f + sc.x) + bb.x,
              (v1 - mean) * inv * (1.0f + sc.y) + bb.y);
    w.y = pk2((v2 - mean) * inv * (1.0f + sc.z) + bb.z,
              (v3 - mean) * inv * (1.0f + sc.w) + bb.w);
    *(uint2*)(out + (size_t)row * 1024 + t * 4) = w;
}

// ---------------- GEMM: C[M,N] = A_bf16[M,K] * B_bf16[N,K]^T + bias (+epilogue) --------
template <int EPI, bool OUTF32, bool RESF32>
__global__ __launch_bounds__(256) void gemm_bt_k(const u16* __restrict__ A,
                                                 const u16* __restrict__ B,
                                                 const float* __restrict__ bias,
                                                 const void* __restrict__ res,
                                                 void* __restrict__ Cv,
                                                 int M, int N, int K) {
    __shared__ __align__(16) u16 As[4096];   // 128 rows x 32 k (DMA layout, unpadded)
    __shared__ __align__(16) u16 Bs[4096];
    const int t = threadIdx.x, wave = t >> 6, lane = t & 63;
    const int quad = lane >> 4, ln = lane & 15;
    const int m0 = blockIdx.y * 128, n0 = blockIdx.x * 128;
    const int wm = (wave >> 1) * 64, wn = (wave & 1) * 64;

    floatx4 acc[4][4];
    for (int mt = 0; mt < 4; mt++) for (int nt = 0; nt < 4; nt++) acc[mt][nt] = (floatx4)0.0f;

    const int c0 = t, c1 = t + 256;
    const u16* Ap0 = A + (size_t)(m0 + (c0 >> 2)) * K + (c0 & 3) * 8;
    const u16* Ap1 = A + (size_t)(m0 + (c1 >> 2)) * K + (c1 & 3) * 8;
    const u16* Bp0 = B + (size_t)(n0 + (c0 >> 2)) * K + (c0 & 3) * 8;
    const u16* Bp1 = B + (size_t)(n0 + (c1 >> 2)) * K + (c1 & 3) * 8;
    u16* AsW0 = As + wave * 512;
    u16* AsW1 = As + 2048 + wave * 512;
    u16* BsW0 = Bs + wave * 512;
    u16* BsW1 = Bs + 2048 + wave * 512;

    for (int kt = 0; kt < K; kt += 32) {
        __syncthreads();
        async16(Ap0 + kt, AsW0);
        async16(Ap1 + kt, AsW1);
        async16(Bp0 + kt, BsW0);
        async16(Bp1 + kt, BsW1);
        __syncthreads();
        short8 af[4], bfr[4];
        for (int mt = 0; mt < 4; mt++)
            af[mt] = *(const short8*)&As[(wm + mt * 16 + ln) * 32 + quad * 8];
        for (int nt = 0; nt < 4; nt++)
            bfr[nt] = *(const short8*)&Bs[(wn + nt * 16 + ln) * 32 + quad * 8];
        for (int mt = 0; mt < 4; mt++)
            for (int nt = 0; nt < 4; nt++)
                acc[mt][nt] = __builtin_amdgcn_mfma_f32_16x16x32_bf16(af[mt], bfr[nt], acc[mt][nt], 0, 0, 0);
    }

    for (int nt = 0; nt < 4; nt++) {
        int col = n0 + wn + nt * 16 + ln;
        float bv = bias[col];
        for (int mt = 0; mt < 4; mt++) {
            for (int r = 0; r < 4; r++) {
                int row = m0 + wm + mt * 16 + quad * 4 + r;
                float v = acc[mt][nt][r] + bv;
                if (EPI == 1) v = fmaxf(v, 0.0f);
                if (EPI == 2) {
                    if (RESF32) v += ((const float*)res)[(size_t)row * N + col];
                    else        v += bf2f(((const u16*)res)[(size_t)row * N + col]);
                }
                if (OUTF32) ((float*)Cv)[(size_t)row * N + col] = v;
                else        ((u16*)Cv)[(size_t)row * N + col] = f2b(v);
            }
        }
    }
}

// ---------------- fused QKV GEMM: q cols scaled by softplus(pds)*LOG2E ----------------
__global__ __launch_bounds__(256) void gemm_qkv_k(const u16* __restrict__ A,
                                                  const u16* __restrict__ B,
                                                  const float* __restrict__ bq,
                                                  const float* __restrict__ bk,
                                                  const float* __restrict__ bv,
                                                  const float* __restrict__ pds,
                                                  u16* __restrict__ C) {
    const int K = 1024, N = 3072;
    __shared__ __align__(16) u16 As[4096];
    __shared__ __align__(16) u16 Bs[4096];
    const int t = threadIdx.x, wave = t >> 6, lane = t & 63;
    const int quad = lane >> 4, ln = lane & 15;
    const int m0 = blockIdx.y * 128, n0 = blockIdx.x * 128;
    const int wm = (wave >> 1) * 64, wn = (wave & 1) * 64;

    floatx4 acc[4][4];
    for (int mt = 0; mt < 4; mt++) for (int nt = 0; nt < 4; nt++) acc[mt][nt] = (floatx4)0.0f;

    const int c0 = t, c1 = t + 256;
    const u16* Ap0 = A + (size_t)(m0 + (c0 >> 2)) * K + (c0 & 3) * 8;
    const u16* Ap1 = A + (size_t)(m0 + (c1 >> 2)) * K + (c1 & 3) * 8;
    const u16* Bp0 = B + (size_t)(n0 + (c0 >> 2)) * K + (c0 & 3) * 8;
    const u16* Bp1 = B + (size_t)(n0 + (c1 >> 2)) * K + (c1 & 3) * 8;
    u16* AsW0 = As + wave * 512;
    u16* AsW1 = As + 2048 + wave * 512;
    u16* BsW0 = Bs + wave * 512;
    u16* BsW1 = Bs + 2048 + wave * 512;

    for (int kt = 0; kt < K; kt += 32) {
        __syncthreads();
        async16(Ap0 + kt, AsW0);
        async16(Ap1 + kt, AsW1);
        async16(Bp0 + kt, BsW0);
        async16(Bp1 + kt, BsW1);
        __syncthreads();
        short8 af[4], bfr[4];
        for (int mt = 0; mt < 4; mt++)
            af[mt] = *(const short8*)&As[(wm + mt * 16 + ln) * 32 + quad * 8];
        for (int nt = 0; nt < 4; nt++)
            bfr[nt] = *(const short8*)&Bs[(wn + nt * 16 + ln) * 32 + quad * 8];
        for (int mt = 0; mt < 4; mt++)
            for (int nt = 0; nt < 4; nt++)
                acc[mt][nt] = __builtin_amdgcn_mfma_f32_16x16x32_bf16(af[mt], bfr[nt], acc[mt][nt], 0, 0, 0);
    }

    for (int nt = 0; nt < 4; nt++) {
        int col = n0 + wn + nt * 16 + ln;
        float bv_, sc = 1.0f;
        if (col < 1024) {
            bv_ = bq[col];
            float xp = pds[col & 63];
            float sp = (xp > 20.0f) ? xp : log1pf(__expf(xp));
            sc = R_PDS * sp * LOG2E;            // fold log2(e): attn uses exp2
        } else if (col < 2048) bv_ = bk[col - 1024];
        else                   bv_ = bv[col - 2048];
        for (int mt = 0; mt < 4; mt++)
            for (int r = 0; r < 4; r++) {
                int row = m0 + wm + mt * 16 + quad * 4 + r;
                C[(size_t)row * N + col] = f2b((acc[mt][nt][r] + bv_) * sc);
            }
    }
}

// ---------------- V transpose: qkv v-part -> vT[bh][d][s] ----------------
__global__ __launch_bounds__(256) void transpose_v_k(const u16* __restrict__ qkv, u16* __restrict__ vT) {
    __shared__ u16 tile[64][65];
    int st = blockIdx.x, bh = blockIdx.y;
    int b = bh >> 4, h = bh & 15;
    const u16* vb = qkv + (size_t)(b * 2048 + st * 64) * 3072 + 2048 + h * 64;
    int t = threadIdx.x;
    for (int i = t; i < 4096; i += 256) {
        int s = i >> 6, d = i & 63;
        tile[s][d] = vb[(size_t)s * 3072 + d];
    }
    __syncthreads();
    u16* ob = vT + (size_t)bh * 131072 + st * 64;
    for (int i = t; i < 4096; i += 256) {
        int d = i >> 6, s = i & 63;
        ob[(size_t)d * 2048 + s] = tile[s][d];
    }
}

// ---------------- flash attention: 1 block = (bh, 64 q rows), BKV=64 -------------------
// LDS 27.6 KB (Ps aliases dead Qs) -> 5 blocks/CU. Named-scalar register prefetch of
// next K/V tile (r5's array+branch spill mode excluded). P = exp2(S): log2e pre-folded
// into q. l via all-ones-B MFMA.
__global__ __launch_bounds__(256) void attn_k(const u16* __restrict__ qkv,
                                              const u16* __restrict__ vT,
                                              const float* __restrict__ mask,
                                              const int* __restrict__ flag,
                                              u16* __restrict__ o) {
    __shared__ __align__(16) u16 QPs[64][72];   // Q during setup, then P
    __shared__ __align__(16) u16 Ks[64][72];
    __shared__ __align__(16) u16 Vs[64][72];    // rows = d, cols = kv

    const int t = threadIdx.x, wave = t >> 6, lane = t & 63;
    const int quad = lane >> 4, ln = lane & 15;
    const int qt = blockIdx.x, bh = blockIdx.y;
    const int b = bh >> 4, h = bh & 15;
    const int q0 = qt * 64;

    // stage Q tile (pre-scaled by softplus*log2e in QKV epilogue)
    const u16* qb = qkv + (size_t)(b * 2048 + q0) * 3072 + h * 64;
    for (int c = t; c < 512; c += 256) {
        int row = c >> 3, seg = c & 7;
        *(uint4*)&QPs[row][seg * 8] = *(const uint4*)(qb + (size_t)row * 3072 + seg * 8);
    }
    __syncthreads();

    // hoist Q fragments; QPs is dead after this (loop-top barrier drains these reads
    // before any wave's P writes can land — __syncthreads emits full lgkmcnt(0) drain)
    short8 qf[2];
    for (int ks = 0; ks < 2; ks++)
        qf[ks] = *(const short8*)&QPs[wave * 16 + ln][ks * 32 + quad * 8];

    short8 ones_f;
    for (int i = 0; i < 8; i++) ones_f[i] = (short)0x3F80;   // bf16 1.0

    floatx4 acc_o[4], acc_l = (floatx4)0.0f;
    for (int dt = 0; dt < 4; dt++) acc_o[dt] = (floatx4)0.0f;

    const int mflag = *flag;
    const u16* kb = qkv + (size_t)(b * 2048) * 3072 + 1024 + h * 64;
    const u16* vg = vT + (size_t)bh * 131072;

    // per-thread staging coordinates: chunks t and t+256 (row += 32, same seg)
    const int r0 = t >> 3, s0 = (t & 7) * 8;
    const u16* kp0 = kb + (size_t)r0 * 3072 + s0;
    const u16* kp1 = kb + (size_t)(r0 + 32) * 3072 + s0;
    const u16* vp0 = vg + (size_t)r0 * 2048 + s0;
    const u16* vp1 = vg + (size_t)(r0 + 32) * 2048 + s0;

    // prefetch tile 0 into named registers
    uint4 kr0 = *(const uint4*)(kp0);
    uint4 kr1 = *(const uint4*)(kp1);
    uint4 vr0 = *(const uint4*)(vp0);
    uint4 vr1 = *(const uint4*)(vp1);

    for (int kv0 = 0; kv0 < 2048; kv0 += 64) {
        __syncthreads();                       // all waves done reading prev Ks/Vs/Ps
        *(uint4*)&Ks[r0][s0]      = kr0;
        *(uint4*)&Ks[r0 + 32][s0] = kr1;
        *(uint4*)&Vs[r0][s0]      = vr0;
        *(uint4*)&Vs[r0 + 32][s0] = vr1;
        __syncthreads();
        if (kv0 + 64 < 2048) {                 // uniform branch; loads overlap compute
            size_t ko = (size_t)(kv0 + 64) * 3072;
            int    vo = kv0 + 64;
            kr0 = *(const uint4*)(kp0 + ko);
            kr1 = *(const uint4*)(kp1 + ko);
            vr0 = *(const uint4*)(vp0 + vo);
            vr1 = *(const uint4*)(vp1 + vo);
        }

        // S = Q K^T  (wave: 16 q rows x 64 kv cols); S already in log2 domain
        floatx4 acc_s[4];
        for (int nt = 0; nt < 4; nt++) acc_s[nt] = (floatx4)0.0f;
        for (int ks = 0; ks < 2; ks++)
            for (int nt = 0; nt < 4; nt++) {
                short8 bfr = *(const short8*)&Ks[nt * 16 + ln][ks * 32 + quad * 8];
                acc_s[nt] = __builtin_amdgcn_mfma_f32_16x16x32_bf16(qf[ks], bfr, acc_s[nt], 0, 0, 0);
            }
        if (mflag) {
            for (int nt = 0; nt < 4; nt++)
                for (int r = 0; r < 4; r++) {
                    int qr = q0 + wave * 16 + quad * 4 + r;
                    int kc = kv0 + nt * 16 + ln;
                    acc_s[nt][r] += mask[(size_t)qr * 2048 + kc] * LOG2E;
                }
        }

        // P = exp2(min(S,80)) -> Ps (bf16); rows wave-local, no barrier needed
        int prow = wave * 16 + quad * 4;
        for (int nt = 0; nt < 4; nt++) {
            unsigned int u01 = pk2(__builtin_amdgcn_exp2f(fminf(acc_s[nt][0], 80.0f)),
                                   __builtin_amdgcn_exp2f(fminf(acc_s[nt][1], 80.0f)));
            unsigned int u23 = pk2(__builtin_amdgcn_exp2f(fminf(acc_s[nt][2], 80.0f)),
                                   __builtin_amdgcn_exp2f(fminf(acc_s[nt][3], 80.0f)));
            QPs[prow + 0][nt * 16 + ln] = (u16)(u01 & 0xffff);
            QPs[prow + 1][nt * 16 + ln] = (u16)(u01 >> 16);
            QPs[prow + 2][nt * 16 + ln] = (u16)(u23 & 0xffff);
            QPs[prow + 3][nt * 16 + ln] = (u16)(u23 >> 16);
        }

        // O += P V ; l += P·1
        for (int ks = 0; ks < 2; ks++) {
            short8 a = *(const short8*)&QPs[wave * 16 + ln][ks * 32 + quad * 8];
            acc_l = __builtin_amdgcn_mfma_f32_16x16x32_bf16(a, ones_f, acc_l, 0, 0, 0);
            for (int dt = 0; dt < 4; dt++) {
                short8 bfr = *(const short8*)&Vs[dt * 16 + ln][ks * 32 + quad * 8];
                acc_o[dt] = __builtin_amdgcn_mfma_f32_16x16x32_bf16(a, bfr, acc_o[dt], 0, 0, 0);
            }
        }
    }

    // write O -> o[b, s, h, d] bf16 (row stride 1024)
    u16* ob = o + (size_t)(b * 2048 + q0) * 1024 + h * 64;
    for (int r = 0; r < 4; r++) {
        float inv = 1.0f / acc_l[r];
        int row = wave * 16 + quad * 4 + r;
        for (int dt = 0; dt < 4; dt++)
            ob[(size_t)row * 1024 + dt * 16 + ln] = f2b(acc_o[dt][r] * inv);
    }
}

extern "C" void kernel_launch(void* const* d_in, const int* in_sizes, int n_in,
                              void* d_out, int out_size, void* d_ws, size_t ws_size,
                              hipStream_t stream) {
    const float* inp    = (const float*)d_in[0];
    const float* mask   = (const float*)d_in[1];
    const float* rms_s  = (const float*)d_in[2];
    const float* Wq     = (const float*)d_in[3];
    const float* bq     = (const float*)d_in[4];
    const float* Wk     = (const float*)d_in[5];
    const float* bk     = (const float*)d_in[6];
    const float* Wv     = (const float*)d_in[7];
    const float* bv     = (const float*)d_in[8];
    const float* pds    = (const float*)d_in[9];
    const float* Wpost  = (const float*)d_in[10];
    const float* bpost  = (const float*)d_in[11];
    const float* ln_s   = (const float*)d_in[12];
    const float* ln_b   = (const float*)d_in[13];
    const float* W1     = (const float*)d_in[14];
    const float* b1     = (const float*)d_in[15];
    const float* W2     = (const float*)d_in[16];
    const float* b2     = (const float*)d_in[17];
    float* out = (float*)d_out;

    char* w = (char*)d_ws;
    const size_t MB = 1u << 20;
    u16* W1b   = (u16*)(w + 0 * MB);      // [0,8)
    u16* W2b   = (u16*)(w + 8 * MB);      // [8,16)
    u16* qkv   = (u16*)(w + 16 * MB);     // [16,64) -> f1 [16,80)
    u16* x     = (u16*)(w + 64 * MB);     // [64,80) -> o
    u16* o     = (u16*)(w + 64 * MB);
    u16* Wqkvb = (u16*)(w + 80 * MB);     // [80,86)
    u16* Wpb   = (u16*)(w + 86 * MB);     // [86,88)
    u16* yln   = (u16*)(w + 80 * MB);     // [80,96) after Wq..p dead
    u16* vT    = (u16*)(w + 96 * MB);     // [96,112) -> hb
    u16* hb    = (u16*)(w + 96 * MB);
    u16* f1    = (u16*)(w + 16 * MB);
    int* flag  = (int*)(w + 112 * MB);

    f2b_all_k<<<12288, 256, 0, stream>>>(Wq, Wk, Wv, Wpost, W1, W2, Wqkvb, Wpb, W1b, W2b, flag);
    mask_any_k<<<4096, 256, 0, stream>>>(mask, flag);

    rmsnorm_k<<<8192, 256, 0, stream>>>(inp, rms_s, x);

    gemm_qkv_k<<<dim3(24, 64), 256, 0, stream>>>(x, Wqkvb, bq, bk, bv, pds, qkv);

    transpose_v_k<<<dim3(32, 64), 256, 0, stream>>>(qkv, vT);

    attn_k<<<dim3(32, 64), 256, 0, stream>>>(qkv, vT, mask, flag, o);

    gemm_bt_k<2, false, true><<<dim3(8, 64), 256, 0, stream>>>(o, Wpb, bpost, inp, hb, 8192, 1024, 1024);

    layernorm_k<<<8192, 256, 0, stream>>>(hb, ln_s, ln_b, yln);

    gemm_bt_k<1, false, true><<<dim3(32, 64), 256, 0, stream>>>(yln, W1b, b1, nullptr, f1, 8192, 4096, 1024);
    gemm_bt_k<2, true, false><<<dim3(8, 64), 256, 0, stream>>>(f1, W2b, b2, hb, out, 8192, 1024, 4096);
}